// Round 2
// baseline (2237.316 us; speedup 1.0000x reference)
//
#include <hip/hip_runtime.h>

// ---------------------------------------------------------------------------
// TransformerEncoderLayerWithMoE on MI355X (gfx950)
// Round 2: attention path in split-bf16 (hi+lo, 3-MFMA) to make router top-2
// selection match the f32 reference; MoE expert path plain bf16.
// ---------------------------------------------------------------------------

typedef __attribute__((ext_vector_type(8))) short short8;   // 8 bf16 = 4 VGPRs
typedef __attribute__((ext_vector_type(4))) short short4v;
typedef __attribute__((ext_vector_type(4))) float floatx4;  // MFMA C/D frag

#define TOKENS 4096
#define DMODEL 1024
#define NHEADS 16
#define DHEAD  64
#define DFF    4096
#define NEXP   8
#define SEQ    1024
#define NPAIR  64   // BATCH*NHEADS

// RNE float->bf16 (finite inputs only)
__device__ inline short f2bf(float f) {
  unsigned u = __builtin_bit_cast(unsigned, f);
  unsigned r = (u + 0x7fffu + ((u >> 16) & 1u)) >> 16;
  return (short)r;
}
__device__ inline float bf2f(short h) {
  return __builtin_bit_cast(float, ((unsigned)(unsigned short)h) << 16);
}

// ---------------------------------------------------------------------------
// NT GEMM: C[m,n] = scale * sum_k A[m,k]*B[n,k] (+bias[n]) (+src)
// SPLIT: A/B given as hi+lo bf16 planes; acc += Ah*Bh + Ah*Bl + Al*Bh
// EPI: 0 = bf16 store, 1 = f32 store (+optional srcadd), 2 = gated atomic scatter
// AMODE: 0 = linear rows, 1 = gathered rows via tokList, 2 = offset rows
// ---------------------------------------------------------------------------
template<int BM, int BN, int WTM, int WTN, int EPI, int AMODE, bool RELU, bool SPLIT>
__global__ void __launch_bounds__((BM / WTM) * (BN / WTN) * 64)
gemm_nt(const short* __restrict__ Ab, const short* __restrict__ Abl, int lda, long sA,
        const short* __restrict__ Bb, const short* __restrict__ Bbl, int ldb, long sB,
        void* __restrict__ Cb, int ldc, long sC,
        int M, int N, int K, float scale,
        const float* __restrict__ bias, int sBias,
        const float* __restrict__ srcadd,
        const int* __restrict__ tokList,
        const float* __restrict__ gateList,
        const int* __restrict__ counts,
        const int* __restrict__ offsets,
        float* __restrict__ scatterOut)
{
  constexpr int WROWS = BM / WTM;
  constexpr int WCOLS = BN / WTN;
  constexpr int NW = WROWS * WCOLS;
  constexpr int THREADS = NW * 64;
  constexpr int MT = WTM / 16;
  constexpr int NT = WTN / 16;
  constexpr int LDSP = 40;                      // padded pitch (shorts)
  constexpr int RA = (BM * 32) / (THREADS * 8);
  constexpr int RB = (BN * 32) / (THREADS * 8);
  constexpr int PLANES = SPLIT ? 2 : 1;

  const int z = blockIdx.z;
  int Mt = M;
  int rowbase = 0;
  const int* tl = nullptr;
  if (AMODE != 0) {
    Mt = counts[z];
    if ((int)blockIdx.x * BM >= Mt) return;
    if (AMODE == 1) tl = tokList + (long)z * TOKENS;
    else rowbase = offsets[z];
  }
  if (EPI == 2) tl = tokList + (long)z * TOKENS;

  const short* A = Ab + (long)z * sA;
  const short* Al = SPLIT ? (Abl + (long)z * sA) : nullptr;
  const short* B = Bb + (long)z * sB;
  const short* Bl = SPLIT ? (Bbl + (long)z * sB) : nullptr;
  const int tid = threadIdx.x;
  const int lane = tid & 63;
  const int w = tid >> 6;
  const int wrow = w % WROWS;
  const int wcol = w / WROWS;
  const int m0 = blockIdx.x * BM;
  const int n0 = blockIdx.y * BN;

  __shared__ short As[PLANES * BM * LDSP];
  __shared__ short Bs[PLANES * BN * LDSP];

  long aoff[RA];
  int alds[RA];
#pragma unroll
  for (int r = 0; r < RA; ++r) {
    int flat = r * THREADS * 8 + tid * 8;
    int row = flat >> 5;            // 32 shorts per k-row
    int g8 = (flat >> 3) & 3;
    int grow;
    if (AMODE == 0) grow = m0 + row;
    else if (AMODE == 1) grow = tl[min(m0 + row, Mt - 1)];
    else grow = rowbase + min(m0 + row, Mt - 1);
    aoff[r] = (long)grow * lda + g8 * 8;
    alds[r] = row * LDSP + g8 * 8;
  }
  long boff[RB];
  int blds[RB];
#pragma unroll
  for (int r = 0; r < RB; ++r) {
    int flat = r * THREADS * 8 + tid * 8;
    int row = flat >> 5;
    int g8 = (flat >> 3) & 3;
    boff[r] = (long)(n0 + row) * ldb + g8 * 8;
    blds[r] = row * LDSP + g8 * 8;
  }

  floatx4 acc[MT][NT];
#pragma unroll
  for (int i = 0; i < MT; ++i)
#pragma unroll
    for (int j = 0; j < NT; ++j) acc[i][j] = floatx4{0.f, 0.f, 0.f, 0.f};

  const int aro = (wrow * WTM + (lane & 15)) * LDSP + ((lane >> 4) << 3);
  const int bro = (wcol * WTN + (lane & 15)) * LDSP + ((lane >> 4) << 3);

  for (int k0 = 0; k0 < K; k0 += 32) {
    __syncthreads();
    short8 avh[RA], bvh[RB], avl[SPLIT ? RA : 1], bvl[SPLIT ? RB : 1];
#pragma unroll
    for (int r = 0; r < RA; ++r) avh[r] = *(const short8*)(A + aoff[r] + k0);
#pragma unroll
    for (int r = 0; r < RB; ++r) bvh[r] = *(const short8*)(B + boff[r] + k0);
    if (SPLIT) {
#pragma unroll
      for (int r = 0; r < RA; ++r) avl[r] = *(const short8*)(Al + aoff[r] + k0);
#pragma unroll
      for (int r = 0; r < RB; ++r) bvl[r] = *(const short8*)(Bl + boff[r] + k0);
    }
#pragma unroll
    for (int r = 0; r < RA; ++r) *(short8*)&As[alds[r]] = avh[r];
#pragma unroll
    for (int r = 0; r < RB; ++r) *(short8*)&Bs[blds[r]] = bvh[r];
    if (SPLIT) {
#pragma unroll
      for (int r = 0; r < RA; ++r) *(short8*)&As[BM * LDSP + alds[r]] = avl[r];
#pragma unroll
      for (int r = 0; r < RB; ++r) *(short8*)&Bs[BN * LDSP + blds[r]] = bvl[r];
    }
    __syncthreads();

    short8 afh[MT], bfh[NT];
#pragma unroll
    for (int i = 0; i < MT; ++i) afh[i] = *(const short8*)&As[aro + i * 16 * LDSP];
#pragma unroll
    for (int j = 0; j < NT; ++j) bfh[j] = *(const short8*)&Bs[bro + j * 16 * LDSP];
    if (SPLIT) {
      short8 afl[MT], bfl[NT];
#pragma unroll
      for (int i = 0; i < MT; ++i) afl[i] = *(const short8*)&As[BM * LDSP + aro + i * 16 * LDSP];
#pragma unroll
      for (int j = 0; j < NT; ++j) bfl[j] = *(const short8*)&Bs[BN * LDSP + bro + j * 16 * LDSP];
#pragma unroll
      for (int i = 0; i < MT; ++i)
#pragma unroll
        for (int j = 0; j < NT; ++j) {
          acc[i][j] = __builtin_amdgcn_mfma_f32_16x16x32_bf16(afh[i], bfh[j], acc[i][j], 0, 0, 0);
          acc[i][j] = __builtin_amdgcn_mfma_f32_16x16x32_bf16(afh[i], bfl[j], acc[i][j], 0, 0, 0);
          acc[i][j] = __builtin_amdgcn_mfma_f32_16x16x32_bf16(afl[i], bfh[j], acc[i][j], 0, 0, 0);
        }
    } else {
#pragma unroll
      for (int i = 0; i < MT; ++i)
#pragma unroll
        for (int j = 0; j < NT; ++j)
          acc[i][j] = __builtin_amdgcn_mfma_f32_16x16x32_bf16(afh[i], bfh[j], acc[i][j], 0, 0, 0);
    }
  }

  // epilogue: C layout col=lane&15, row=(lane>>4)*4+q
  const float* bz = bias ? (bias + (long)z * sBias) : nullptr;
#pragma unroll
  for (int i = 0; i < MT; ++i) {
    int rt = wrow * WTM + i * 16 + ((lane >> 4) << 2);
#pragma unroll
    for (int j = 0; j < NT; ++j) {
      int col = n0 + wcol * WTN + j * 16 + (lane & 15);
      float badd = bz ? bz[col] : 0.f;
      floatx4 v = acc[i][j];
#pragma unroll
      for (int q = 0; q < 4; ++q) {
        int r = m0 + rt + q;
        if (AMODE != 0 && r >= Mt) break;
        float val = v[q] * scale + badd;
        if (RELU) val = fmaxf(val, 0.f);
        if (EPI == 0) {
          long orow = (AMODE == 1) ? (long)(offsets[z] + r) : (long)r;
          ((short*)Cb)[(long)z * sC + orow * ldc + col] = f2bf(val);
        } else if (EPI == 1) {
          float* Cf = (float*)Cb + (long)z * sC;
          if (srcadd) val += srcadd[(long)r * ldc + col];
          Cf[(long)r * ldc + col] = val;
        } else {
          int tok = tl[r];
          float gate = gateList[(long)z * TOKENS + r];
          atomicAdd(&scatterOut[(long)tok * DMODEL + col], gate * val);
        }
      }
    }
  }
}

// f32 -> hi/lo bf16 planes
__global__ void split_bf16(const float* __restrict__ src, short* __restrict__ hi,
                           short* __restrict__ lo, int n) {
  int i = (blockIdx.x * 256 + threadIdx.x) * 4;
  if (i >= n) return;
  float4 v = *(const float4*)(src + i);
  short h0 = f2bf(v.x), h1 = f2bf(v.y), h2 = f2bf(v.z), h3 = f2bf(v.w);
  short4v oh = { h0, h1, h2, h3 };
  short4v ol = { f2bf(v.x - bf2f(h0)), f2bf(v.y - bf2f(h1)),
                 f2bf(v.z - bf2f(h2)), f2bf(v.w - bf2f(h3)) };
  *(short4v*)(hi + i) = oh;
  *(short4v*)(lo + i) = ol;
}

// f32 [R,C] -> bf16 [C,R] per batch z (R,C multiples of 64)
__global__ void transpose_bf16(const float* __restrict__ src, short* __restrict__ dst,
                               int R, int C) {
  __shared__ float t[64][65];
  long zoff = (long)blockIdx.z * R * C;
  const float* s = src + zoff;
  short* d = dst + zoff;
  int r0 = blockIdx.y * 64, c0 = blockIdx.x * 64;
  int tid = threadIdx.x;
#pragma unroll
  for (int i = 0; i < 16; ++i) {
    int flat = i * 256 + tid;
    int r = flat >> 6, c = flat & 63;
    t[r][c] = s[(long)(r0 + r) * C + c0 + c];
  }
  __syncthreads();
#pragma unroll
  for (int i = 0; i < 16; ++i) {
    int flat = i * 256 + tid;
    int c = flat >> 6, r = flat & 63;
    d[(long)(c0 + c) * R + r0 + r] = f2bf(t[r][c]);
  }
}

// qkv f32 [T,3072] -> Q,K hi/lo [pair][S][dh], Vt hi/lo [pair][dh][S]
__global__ void repack_qkv_split(const float* __restrict__ qkv,
                                 short* __restrict__ Qh, short* __restrict__ Ql,
                                 short* __restrict__ Kh, short* __restrict__ Kl,
                                 short* __restrict__ Vh, short* __restrict__ Vl) {
  long idx = (long)blockIdx.x * 256 + threadIdx.x;
  int t = (int)(idx / 3072), c = (int)(idx % 3072);
  int sec = c >> 10, within = c & 1023;
  int h = within >> 6, di = within & 63;
  int b = t >> 10, s = t & 1023;
  int g = b * NHEADS + h;
  float v = qkv[idx];
  short vh = f2bf(v);
  short vl = f2bf(v - bf2f(vh));
  if (sec == 2) {
    long vo = (long)g * 65536 + di * 1024 + s;
    Vh[vo] = vh; Vl[vo] = vl;
  } else {
    long qo = (long)g * 65536 + s * 64 + di;
    if (sec == 0) { Qh[qo] = vh; Ql[qo] = vl; }
    else          { Kh[qo] = vh; Kl[qo] = vl; }
  }
}

// row softmax on f32, write P as hi plane [0,1024) + lo plane [1024,2048) shorts
__global__ void softmax_rows_split(float* __restrict__ scores) {
  __shared__ float wred[4], wsum[4];
  long row = blockIdx.x;
  float* p = scores + row * 1024;
  int tid = threadIdx.x;
  float4 v = *(const float4*)(p + tid * 4);
  float mx = fmaxf(fmaxf(v.x, v.y), fmaxf(v.z, v.w));
  for (int m = 1; m < 64; m <<= 1) mx = fmaxf(mx, __shfl_xor(mx, m));
  if ((tid & 63) == 0) wred[tid >> 6] = mx;
  __syncthreads();
  mx = fmaxf(fmaxf(wred[0], wred[1]), fmaxf(wred[2], wred[3]));
  float e0 = expf(v.x - mx), e1 = expf(v.y - mx), e2 = expf(v.z - mx), e3 = expf(v.w - mx);
  float sm = e0 + e1 + e2 + e3;
  for (int m = 1; m < 64; m <<= 1) sm += __shfl_xor(sm, m);
  if ((tid & 63) == 0) wsum[tid >> 6] = sm;
  __syncthreads();
  float inv = 1.f / (wsum[0] + wsum[1] + wsum[2] + wsum[3]);
  float y0 = e0 * inv, y1 = e1 * inv, y2 = e2 * inv, y3 = e3 * inv;
  short h0 = f2bf(y0), h1 = f2bf(y1), h2 = f2bf(y2), h3 = f2bf(y3);
  short4v oh = { h0, h1, h2, h3 };
  short4v ol = { f2bf(y0 - bf2f(h0)), f2bf(y1 - bf2f(h1)),
                 f2bf(y2 - bf2f(h2)), f2bf(y3 - bf2f(h3)) };
  short* ps = (short*)p;
  *(short4v*)(ps + tid * 4) = oh;
  *(short4v*)(ps + 1024 + tid * 4) = ol;
}

// layer norm over rows of 1024; optional f32 and bf16 outputs
__global__ void ln_rows(const float* __restrict__ x, const float* __restrict__ g,
                        const float* __restrict__ b, float* __restrict__ of,
                        short* __restrict__ ob) {
  __shared__ float ws1[4], ws2[4];
  long row = blockIdx.x;
  const float* p = x + row * 1024;
  int tid = threadIdx.x;
  float4 v = *(const float4*)(p + tid * 4);
  float s = v.x + v.y + v.z + v.w;
  float s2 = v.x * v.x + v.y * v.y + v.z * v.z + v.w * v.w;
  for (int m = 1; m < 64; m <<= 1) { s += __shfl_xor(s, m); s2 += __shfl_xor(s2, m); }
  if ((tid & 63) == 0) { ws1[tid >> 6] = s; ws2[tid >> 6] = s2; }
  __syncthreads();
  s = ws1[0] + ws1[1] + ws1[2] + ws1[3];
  s2 = ws2[0] + ws2[1] + ws2[2] + ws2[3];
  float mean = s * (1.f / 1024.f);
  float var = s2 * (1.f / 1024.f) - mean * mean;
  float rstd = rsqrtf(var + 1e-5f);
  float4 gg = *(const float4*)(g + tid * 4);
  float4 bb = *(const float4*)(b + tid * 4);
  float y0 = (v.x - mean) * rstd * gg.x + bb.x;
  float y1 = (v.y - mean) * rstd * gg.y + bb.y;
  float y2 = (v.z - mean) * rstd * gg.z + bb.z;
  float y3 = (v.w - mean) * rstd * gg.w + bb.w;
  if (of) { float4 o = { y0, y1, y2, y3 }; *(float4*)(of + row * 1024 + tid * 4) = o; }
  if (ob) { short4v o = { f2bf(y0), f2bf(y1), f2bf(y2), f2bf(y3) }; *(short4v*)(ob + row * 1024 + tid * 4) = o; }
}

// router: one wave per token, f64 accumulation for stable top-2 selection
__global__ void router_kernel(const float* __restrict__ x, const float* __restrict__ rw,
                              const float* __restrict__ rb,
                              float* __restrict__ probsum, int* __restrict__ cursor,
                              int* __restrict__ tokList, float* __restrict__ gateList) {
  int w = threadIdx.x >> 6, lane = threadIdx.x & 63;
  int t = blockIdx.x * 4 + w;
  const float* xp = x + (long)t * 1024;
  float xv[16];
#pragma unroll
  for (int i = 0; i < 16; ++i) xv[i] = xp[lane + i * 64];
  float logit[8];
#pragma unroll
  for (int e = 0; e < 8; ++e) {
    const float* wp = rw + e * 1024;
    double a = 0.0;
#pragma unroll
    for (int i = 0; i < 16; ++i) a += (double)xv[i] * (double)wp[lane + i * 64];
    for (int m = 1; m < 64; m <<= 1) a += __shfl_xor(a, m);
    logit[e] = (float)a + rb[e];
  }
  float mx = logit[0];
#pragma unroll
  for (int e = 1; e < 8; ++e) mx = fmaxf(mx, logit[e]);
  float pe[8], sum = 0.f;
#pragma unroll
  for (int e = 0; e < 8; ++e) { pe[e] = expf(logit[e] - mx); sum += pe[e]; }
  float inv = 1.f / sum;
#pragma unroll
  for (int e = 0; e < 8; ++e) pe[e] *= inv;
  int i1 = 0;
#pragma unroll
  for (int e = 1; e < 8; ++e) if (pe[e] > pe[i1]) i1 = e;
  int i2 = (i1 == 0) ? 1 : 0;
#pragma unroll
  for (int e = 0; e < 8; ++e) if (e != i1 && pe[e] > pe[i2]) i2 = e;
  float denom = pe[i1] + pe[i2];
  float g1 = pe[i1] / denom, g2 = pe[i2] / denom;
  if (lane == 0) {
    for (int e = 0; e < 8; ++e) atomicAdd(&probsum[e], pe[e]);
    int p1 = atomicAdd(&cursor[i1], 1);
    tokList[i1 * TOKENS + p1] = t; gateList[i1 * TOKENS + p1] = g1;
    int p2 = atomicAdd(&cursor[i2], 1);
    tokList[i2 * TOKENS + p2] = t; gateList[i2 * TOKENS + p2] = g2;
  }
}

__global__ void finalize_kernel(const int* __restrict__ cursor, const float* __restrict__ probsum,
                                int* __restrict__ offsets, float* __restrict__ lb_out) {
  if (threadIdx.x == 0) {
    int off = 0; float lb = 0.f;
    for (int e = 0; e < 8; ++e) {
      offsets[e] = off; off += cursor[e];
      float f = (float)cursor[e] / (float)(2 * TOKENS);
      float P = probsum[e] / (float)TOKENS;
      lb += f * P;
    }
    *lb_out = 8.f * lb;
  }
}

__global__ void sentinel_kernel(float* out, int n) {
  if (threadIdx.x == 0) { out[0] = 1e9f; out[n - 1] = 1e9f; }
}

// ---------------------------------------------------------------------------
extern "C" void kernel_launch(void* const* d_in, const int* in_sizes, int n_in,
                              void* d_out, int out_size, void* d_ws, size_t ws_size,
                              hipStream_t stream) {
  const float* src        = (const float*)d_in[0];
  const float* in_proj_w  = (const float*)d_in[1];
  const float* in_proj_b  = (const float*)d_in[2];
  const float* out_proj_w = (const float*)d_in[3];
  const float* out_proj_b = (const float*)d_in[4];
  const float* ln1_g      = (const float*)d_in[5];
  const float* ln1_b      = (const float*)d_in[6];
  const float* router_w   = (const float*)d_in[7];
  const float* router_b   = (const float*)d_in[8];
  const float* w1         = (const float*)d_in[9];
  const float* b1         = (const float*)d_in[10];
  const float* w2         = (const float*)d_in[11];
  const float* b2         = (const float*)d_in[12];
  const float* ln2_g      = (const float*)d_in[13];
  const float* ln2_b      = (const float*)d_in[14];
  float* out = (float*)d_out;

  char* ws = (char*)d_ws;
  size_t off = 0;
  auto alloc = [&](size_t bytes) -> char* {
    char* p = ws + off;
    off += (bytes + 255) & ~(size_t)255;
    return p;
  };
  // big block: Q/K/V hi+lo planes during attention; w1t/w2t after
  char*  blockW = alloc(8ll * (DFF * DMODEL + DMODEL * DFF) * 2);  // 128MB
  short* Qh = (short*)(blockW + 0ll  * 1024 * 1024);
  short* Ql = (short*)(blockW + 8ll  * 1024 * 1024);
  short* Kh = (short*)(blockW + 16ll * 1024 * 1024);
  short* Kl = (short*)(blockW + 24ll * 1024 * 1024);
  short* Vh = (short*)(blockW + 32ll * 1024 * 1024);
  short* Vl = (short*)(blockW + 40ll * 1024 * 1024);
  short* w1t = (short*)blockW;                                      // [E][dff][d]
  short* w2t = (short*)(blockW + 8ll * DFF * DMODEL * 2);           // [E][d][dff]
  short* winh  = (short*)alloc(3072ll * 1024 * 2);
  short* winl  = (short*)alloc(3072ll * 1024 * 2);
  short* wouth = (short*)alloc(1024ll * 1024 * 2);
  short* woutl = (short*)alloc(1024ll * 1024 * 2);
  short* xh    = (short*)alloc((long)TOKENS * DMODEL * 2);
  short* xl    = (short*)alloc((long)TOKENS * DMODEL * 2);
  char*  reg1  = alloc((long)TOKENS * 3072 * 4);     // 48MB: qkv f32 -> O f32/Ohi/Olo/x1
  float* qkvf  = (float*)reg1;
  float* Of32  = (float*)reg1;
  short* Ohi   = (short*)(reg1 + 16ll * 1024 * 1024);
  short* Olo   = (short*)(reg1 + 24ll * 1024 * 1024);
  float* x1    = (float*)(reg1 + 32ll * 1024 * 1024);
  char*  reg2  = alloc(16ll * 1024 * 1024 * 4);      // 64MB: scores chunk -> h
  float* scores = (float*)reg2;
  short* h      = (short*)reg2;
  short* x1nbf = (short*)alloc((long)TOKENS * DMODEL * 2);
  float* accum = (float*)alloc((long)TOKENS * DMODEL * 4);
  float* probsum = (float*)alloc(64);
  int*   cursor  = (int*)(probsum + 8);
  int*   eoff    = (int*)alloc(32);
  int*   tokList = (int*)alloc(8ll * TOKENS * 4);
  float* gateList= (float*)alloc(8ll * TOKENS * 4);
  size_t needed = off;

  if (ws_size < needed) {
    sentinel_kernel<<<1, 64, 0, stream>>>(out, out_size);
    return;
  }

  hipMemsetAsync(probsum, 0, 64, stream);

  // splits of f32 inputs
  split_bf16<<<3072 * 1024 / 1024, 256, 0, stream>>>(in_proj_w, winh, winl, 3072 * 1024);
  split_bf16<<<1024 * 1024 / 1024, 256, 0, stream>>>(out_proj_w, wouth, woutl, 1024 * 1024);
  split_bf16<<<TOKENS * DMODEL / 1024, 256, 0, stream>>>(src, xh, xl, TOKENS * DMODEL);

  // QKV projection (split): qkv f32 = x @ win^T + b
  gemm_nt<128, 128, 64, 64, 1, 0, false, true><<<dim3(32, 24, 1), 256, 0, stream>>>(
      xh, xl, 1024, 0, winh, winl, 1024, 0, qkvf, 3072, 0,
      TOKENS, 3072, 1024, 1.f, in_proj_b, 0, nullptr, nullptr, nullptr, nullptr, nullptr, nullptr);
  repack_qkv_split<<<(int)((long)TOKENS * 3072 / 256), 256, 0, stream>>>(qkvf, Qh, Ql, Kh, Kl, Vh, Vl);

  // attention, chunked by batch (16 pairs per chunk)
  for (int c = 0; c < 4; ++c) {
    long co = (long)c * 16 * 65536;
    gemm_nt<128, 128, 64, 64, 1, 0, false, true><<<dim3(8, 8, 16), 256, 0, stream>>>(
        Qh + co, Ql + co, 64, 65536, Kh + co, Kl + co, 64, 65536, scores, 1024, 1048576,
        1024, 1024, 64, 0.125f, nullptr, 0, nullptr, nullptr, nullptr, nullptr, nullptr, nullptr);
    softmax_rows_split<<<16 * 1024, 256, 0, stream>>>(scores);
    // P(hi/lo in place, pitch 2048 shorts) @ V^T -> O f32
    gemm_nt<128, 64, 64, 32, 1, 0, false, true><<<dim3(8, 1, 16), 256, 0, stream>>>(
        (const short*)scores, (const short*)scores + 1024, 2048, 2097152,
        Vh + co, Vl + co, 1024, 65536,
        Of32 + (long)c * 1048576, 1024, 64,
        1024, 64, 1024, 1.f, nullptr, 0, nullptr, nullptr, nullptr, nullptr, nullptr, nullptr);
  }

  // expert weight transposes now (blockW's Q/K/V no longer needed)
  transpose_bf16<<<dim3(DFF / 64, DMODEL / 64, 8), 256, 0, stream>>>(w1, w1t, DMODEL, DFF);
  transpose_bf16<<<dim3(DMODEL / 64, DFF / 64, 8), 256, 0, stream>>>(w2, w2t, DFF, DMODEL);

  // split O, then out-projection (split) + bias + residual(src) -> x1 f32
  split_bf16<<<TOKENS * DMODEL / 1024, 256, 0, stream>>>(Of32, Ohi, Olo, TOKENS * DMODEL);
  gemm_nt<128, 128, 64, 64, 1, 0, false, true><<<dim3(32, 8, 1), 256, 0, stream>>>(
      Ohi, Olo, 1024, 0, wouth, woutl, 1024, 0, x1, 1024, 0,
      TOKENS, 1024, 1024, 1.f, out_proj_b, 0, src, nullptr, nullptr, nullptr, nullptr, nullptr);

  // LN1 -> accum (f32 residual base) + x1nbf (bf16 expert input)
  ln_rows<<<TOKENS, 256, 0, stream>>>(x1, ln1_g, ln1_b, accum, x1nbf);

  // router + expert assignment
  router_kernel<<<TOKENS / 4, 256, 0, stream>>>(accum, router_w, router_b,
                                                probsum, cursor, tokList, gateList);
  finalize_kernel<<<1, 64, 0, stream>>>(cursor, probsum, eoff, out + (out_size - 1));

  // expert GEMM1: h = relu(gather(x1nbf) @ w1t[e]^T + b1[e])
  gemm_nt<128, 128, 64, 64, 0, 1, true, false><<<dim3(32, 32, 8), 256, 0, stream>>>(
      x1nbf, nullptr, 1024, 0, w1t, nullptr, 1024, (long)DFF * DMODEL, h, DFF, 0,
      0, DFF, 1024, 1.f, b1, DFF, nullptr, tokList, nullptr, cursor, eoff, nullptr);

  // expert GEMM2: accum[tok] += gate * (h @ w2t[e]^T + b2[e])
  gemm_nt<128, 128, 64, 64, 2, 2, false, false><<<dim3(32, 8, 8), 256, 0, stream>>>(
      h, nullptr, DFF, 0, w2t, nullptr, DFF, (long)DMODEL * DFF, nullptr, 0, 0,
      0, DMODEL, DFF, 1.f, b2, DMODEL, nullptr, tokList, gateList, cursor, eoff, accum);

  // LN2 -> final output
  ln_rows<<<TOKENS, 256, 0, stream>>>(accum, ln2_g, ln2_b, out, nullptr);
}

// Round 3
// 1697.623 us; speedup vs baseline: 1.3179x; 1.3179x over previous
//
#include <hip/hip_runtime.h>

// ---------------------------------------------------------------------------
// TransformerEncoderLayerWithMoE on MI355X (gfx950)
// Round 3: atomic-free router (counting-sort token lists) + store-based MoE
// combine fused into LN2. Attention stays split-bf16 (hi+lo, 3-MFMA).
// ---------------------------------------------------------------------------

typedef __attribute__((ext_vector_type(8))) short short8;   // 8 bf16 = 4 VGPRs
typedef __attribute__((ext_vector_type(4))) short short4v;
typedef __attribute__((ext_vector_type(4))) float floatx4;  // MFMA C/D frag

#define TOKENS 4096
#define DMODEL 1024
#define NHEADS 16
#define DHEAD  64
#define DFF    4096
#define NEXP   8
#define SEQ    1024
#define NPAIR  64   // BATCH*NHEADS

// RNE float->bf16 (finite inputs only)
__device__ inline short f2bf(float f) {
  unsigned u = __builtin_bit_cast(unsigned, f);
  unsigned r = (u + 0x7fffu + ((u >> 16) & 1u)) >> 16;
  return (short)r;
}
__device__ inline float bf2f(short h) {
  return __builtin_bit_cast(float, ((unsigned)(unsigned short)h) << 16);
}

// ---------------------------------------------------------------------------
// NT GEMM: C[m,n] = scale * sum_k A[m,k]*B[n,k] (+bias[n]) (+src)
// SPLIT: A/B given as hi+lo bf16 planes; acc += Ah*Bh + Ah*Bl + Al*Bh
// EPI: 0 = bf16 store, 1 = f32 store (+optional srcadd)
// AMODE: 0 = linear rows, 1 = gathered rows via packed tokList, 2 = offset rows
// For AMODE!=0, output row = offsets[z] + local_row (packed layout).
// ---------------------------------------------------------------------------
template<int BM, int BN, int WTM, int WTN, int EPI, int AMODE, bool RELU, bool SPLIT>
__global__ void __launch_bounds__((BM / WTM) * (BN / WTN) * 64)
gemm_nt(const short* __restrict__ Ab, const short* __restrict__ Abl, int lda, long sA,
        const short* __restrict__ Bb, const short* __restrict__ Bbl, int ldb, long sB,
        void* __restrict__ Cb, int ldc, long sC,
        int M, int N, int K, float scale,
        const float* __restrict__ bias, int sBias,
        const float* __restrict__ srcadd,
        const int* __restrict__ tokList,
        const int* __restrict__ counts,
        const int* __restrict__ offsets)
{
  constexpr int WROWS = BM / WTM;
  constexpr int WCOLS = BN / WTN;
  constexpr int NW = WROWS * WCOLS;
  constexpr int THREADS = NW * 64;
  constexpr int MT = WTM / 16;
  constexpr int NT = WTN / 16;
  constexpr int LDSP = 40;                      // padded pitch (shorts)
  constexpr int RA = (BM * 32) / (THREADS * 8);
  constexpr int RB = (BN * 32) / (THREADS * 8);
  constexpr int PLANES = SPLIT ? 2 : 1;

  const int z = blockIdx.z;
  int Mt = M;
  int rowbase = 0;
  const int* tl = nullptr;
  if (AMODE != 0) {
    Mt = counts[z];
    if ((int)blockIdx.x * BM >= Mt) return;
    if (AMODE == 1) tl = tokList + offsets[z];
    else rowbase = offsets[z];
  }

  const short* A = Ab + (long)z * sA;
  const short* Al = SPLIT ? (Abl + (long)z * sA) : nullptr;
  const short* B = Bb + (long)z * sB;
  const short* Bl = SPLIT ? (Bbl + (long)z * sB) : nullptr;
  const int tid = threadIdx.x;
  const int lane = tid & 63;
  const int w = tid >> 6;
  const int wrow = w % WROWS;
  const int wcol = w / WROWS;
  const int m0 = blockIdx.x * BM;
  const int n0 = blockIdx.y * BN;

  __shared__ short As[PLANES * BM * LDSP];
  __shared__ short Bs[PLANES * BN * LDSP];

  long aoff[RA];
  int alds[RA];
#pragma unroll
  for (int r = 0; r < RA; ++r) {
    int flat = r * THREADS * 8 + tid * 8;
    int row = flat >> 5;            // 32 shorts per k-row
    int g8 = (flat >> 3) & 3;
    int grow;
    if (AMODE == 0) grow = m0 + row;
    else if (AMODE == 1) grow = tl[min(m0 + row, Mt - 1)];
    else grow = rowbase + min(m0 + row, Mt - 1);
    aoff[r] = (long)grow * lda + g8 * 8;
    alds[r] = row * LDSP + g8 * 8;
  }
  long boff[RB];
  int blds[RB];
#pragma unroll
  for (int r = 0; r < RB; ++r) {
    int flat = r * THREADS * 8 + tid * 8;
    int row = flat >> 5;
    int g8 = (flat >> 3) & 3;
    boff[r] = (long)(n0 + row) * ldb + g8 * 8;
    blds[r] = row * LDSP + g8 * 8;
  }

  floatx4 acc[MT][NT];
#pragma unroll
  for (int i = 0; i < MT; ++i)
#pragma unroll
    for (int j = 0; j < NT; ++j) acc[i][j] = floatx4{0.f, 0.f, 0.f, 0.f};

  const int aro = (wrow * WTM + (lane & 15)) * LDSP + ((lane >> 4) << 3);
  const int bro = (wcol * WTN + (lane & 15)) * LDSP + ((lane >> 4) << 3);

  for (int k0 = 0; k0 < K; k0 += 32) {
    __syncthreads();
    short8 avh[RA], bvh[RB], avl[SPLIT ? RA : 1], bvl[SPLIT ? RB : 1];
#pragma unroll
    for (int r = 0; r < RA; ++r) avh[r] = *(const short8*)(A + aoff[r] + k0);
#pragma unroll
    for (int r = 0; r < RB; ++r) bvh[r] = *(const short8*)(B + boff[r] + k0);
    if (SPLIT) {
#pragma unroll
      for (int r = 0; r < RA; ++r) avl[r] = *(const short8*)(Al + aoff[r] + k0);
#pragma unroll
      for (int r = 0; r < RB; ++r) bvl[r] = *(const short8*)(Bl + boff[r] + k0);
    }
#pragma unroll
    for (int r = 0; r < RA; ++r) *(short8*)&As[alds[r]] = avh[r];
#pragma unroll
    for (int r = 0; r < RB; ++r) *(short8*)&Bs[blds[r]] = bvh[r];
    if (SPLIT) {
#pragma unroll
      for (int r = 0; r < RA; ++r) *(short8*)&As[BM * LDSP + alds[r]] = avl[r];
#pragma unroll
      for (int r = 0; r < RB; ++r) *(short8*)&Bs[BN * LDSP + blds[r]] = bvl[r];
    }
    __syncthreads();

    short8 afh[MT], bfh[NT];
#pragma unroll
    for (int i = 0; i < MT; ++i) afh[i] = *(const short8*)&As[aro + i * 16 * LDSP];
#pragma unroll
    for (int j = 0; j < NT; ++j) bfh[j] = *(const short8*)&Bs[bro + j * 16 * LDSP];
    if (SPLIT) {
      short8 afl[MT], bfl[NT];
#pragma unroll
      for (int i = 0; i < MT; ++i) afl[i] = *(const short8*)&As[BM * LDSP + aro + i * 16 * LDSP];
#pragma unroll
      for (int j = 0; j < NT; ++j) bfl[j] = *(const short8*)&Bs[BN * LDSP + bro + j * 16 * LDSP];
#pragma unroll
      for (int i = 0; i < MT; ++i)
#pragma unroll
        for (int j = 0; j < NT; ++j) {
          acc[i][j] = __builtin_amdgcn_mfma_f32_16x16x32_bf16(afh[i], bfh[j], acc[i][j], 0, 0, 0);
          acc[i][j] = __builtin_amdgcn_mfma_f32_16x16x32_bf16(afh[i], bfl[j], acc[i][j], 0, 0, 0);
          acc[i][j] = __builtin_amdgcn_mfma_f32_16x16x32_bf16(afl[i], bfh[j], acc[i][j], 0, 0, 0);
        }
    } else {
#pragma unroll
      for (int i = 0; i < MT; ++i)
#pragma unroll
        for (int j = 0; j < NT; ++j)
          acc[i][j] = __builtin_amdgcn_mfma_f32_16x16x32_bf16(afh[i], bfh[j], acc[i][j], 0, 0, 0);
    }
  }

  // epilogue: C layout col=lane&15, row=(lane>>4)*4+q
  const float* bz = bias ? (bias + (long)z * sBias) : nullptr;
#pragma unroll
  for (int i = 0; i < MT; ++i) {
    int rt = wrow * WTM + i * 16 + ((lane >> 4) << 2);
#pragma unroll
    for (int j = 0; j < NT; ++j) {
      int col = n0 + wcol * WTN + j * 16 + (lane & 15);
      float badd = bz ? bz[col] : 0.f;
      floatx4 v = acc[i][j];
#pragma unroll
      for (int q = 0; q < 4; ++q) {
        int r = m0 + rt + q;
        if (AMODE != 0 && r >= Mt) break;
        float val = v[q] * scale + badd;
        if (RELU) val = fmaxf(val, 0.f);
        long orow = (AMODE != 0) ? (long)(rowbase + ((AMODE == 1) ? r : 0) + ((AMODE == 1) ? 0 : r))
                                 : (long)r;
        if (AMODE == 1) orow = (long)offsets[z] + r;
        if (EPI == 0) {
          ((short*)Cb)[(long)z * sC + orow * ldc + col] = f2bf(val);
        } else {
          float* Cf = (float*)Cb + (long)z * sC;
          if (srcadd) val += srcadd[orow * ldc + col];
          Cf[orow * ldc + col] = val;
        }
      }
    }
  }
}

// f32 -> hi/lo bf16 planes
__global__ void split_bf16(const float* __restrict__ src, short* __restrict__ hi,
                           short* __restrict__ lo, int n) {
  int i = (blockIdx.x * 256 + threadIdx.x) * 4;
  if (i >= n) return;
  float4 v = *(const float4*)(src + i);
  short h0 = f2bf(v.x), h1 = f2bf(v.y), h2 = f2bf(v.z), h3 = f2bf(v.w);
  short4v oh = { h0, h1, h2, h3 };
  short4v ol = { f2bf(v.x - bf2f(h0)), f2bf(v.y - bf2f(h1)),
                 f2bf(v.z - bf2f(h2)), f2bf(v.w - bf2f(h3)) };
  *(short4v*)(hi + i) = oh;
  *(short4v*)(lo + i) = ol;
}

// f32 [R,C] -> bf16 [C,R] per batch z (R,C multiples of 64)
__global__ void transpose_bf16(const float* __restrict__ src, short* __restrict__ dst,
                               int R, int C) {
  __shared__ float t[64][65];
  long zoff = (long)blockIdx.z * R * C;
  const float* s = src + zoff;
  short* d = dst + zoff;
  int r0 = blockIdx.y * 64, c0 = blockIdx.x * 64;
  int tid = threadIdx.x;
#pragma unroll
  for (int i = 0; i < 16; ++i) {
    int flat = i * 256 + tid;
    int r = flat >> 6, c = flat & 63;
    t[r][c] = s[(long)(r0 + r) * C + c0 + c];
  }
  __syncthreads();
#pragma unroll
  for (int i = 0; i < 16; ++i) {
    int flat = i * 256 + tid;
    int c = flat >> 6, r = flat & 63;
    d[(long)(c0 + c) * R + r0 + r] = f2bf(t[r][c]);
  }
}

// qkv f32 [T,3072] -> Q,K hi/lo [pair][S][dh], Vt hi/lo [pair][dh][S]
__global__ void repack_qkv_split(const float* __restrict__ qkv,
                                 short* __restrict__ Qh, short* __restrict__ Ql,
                                 short* __restrict__ Kh, short* __restrict__ Kl,
                                 short* __restrict__ Vh, short* __restrict__ Vl) {
  long idx = (long)blockIdx.x * 256 + threadIdx.x;
  int t = (int)(idx / 3072), c = (int)(idx % 3072);
  int sec = c >> 10, within = c & 1023;
  int h = within >> 6, di = within & 63;
  int b = t >> 10, s = t & 1023;
  int g = b * NHEADS + h;
  float v = qkv[idx];
  short vh = f2bf(v);
  short vl = f2bf(v - bf2f(vh));
  if (sec == 2) {
    long vo = (long)g * 65536 + di * 1024 + s;
    Vh[vo] = vh; Vl[vo] = vl;
  } else {
    long qo = (long)g * 65536 + s * 64 + di;
    if (sec == 0) { Qh[qo] = vh; Ql[qo] = vl; }
    else          { Kh[qo] = vh; Kl[qo] = vl; }
  }
}

// row softmax on f32, write P as hi plane [0,1024) + lo plane [1024,2048) shorts
__global__ void softmax_rows_split(float* __restrict__ scores) {
  __shared__ float wred[4], wsum[4];
  long row = blockIdx.x;
  float* p = scores + row * 1024;
  int tid = threadIdx.x;
  float4 v = *(const float4*)(p + tid * 4);
  float mx = fmaxf(fmaxf(v.x, v.y), fmaxf(v.z, v.w));
  for (int m = 1; m < 64; m <<= 1) mx = fmaxf(mx, __shfl_xor(mx, m));
  if ((tid & 63) == 0) wred[tid >> 6] = mx;
  __syncthreads();
  mx = fmaxf(fmaxf(wred[0], wred[1]), fmaxf(wred[2], wred[3]));
  float e0 = expf(v.x - mx), e1 = expf(v.y - mx), e2 = expf(v.z - mx), e3 = expf(v.w - mx);
  float sm = e0 + e1 + e2 + e3;
  for (int m = 1; m < 64; m <<= 1) sm += __shfl_xor(sm, m);
  if ((tid & 63) == 0) wsum[tid >> 6] = sm;
  __syncthreads();
  float inv = 1.f / (wsum[0] + wsum[1] + wsum[2] + wsum[3]);
  float y0 = e0 * inv, y1 = e1 * inv, y2 = e2 * inv, y3 = e3 * inv;
  short h0 = f2bf(y0), h1 = f2bf(y1), h2 = f2bf(y2), h3 = f2bf(y3);
  short4v oh = { h0, h1, h2, h3 };
  short4v ol = { f2bf(y0 - bf2f(h0)), f2bf(y1 - bf2f(h1)),
                 f2bf(y2 - bf2f(h2)), f2bf(y3 - bf2f(h3)) };
  short* ps = (short*)p;
  *(short4v*)(ps + tid * 4) = oh;
  *(short4v*)(ps + 1024 + tid * 4) = ol;
}

// layer norm over rows of 1024; optional f32 and bf16 outputs
__global__ void ln_rows(const float* __restrict__ x, const float* __restrict__ g,
                        const float* __restrict__ b, float* __restrict__ of,
                        short* __restrict__ ob) {
  __shared__ float ws1[4], ws2[4];
  long row = blockIdx.x;
  const float* p = x + row * 1024;
  int tid = threadIdx.x;
  float4 v = *(const float4*)(p + tid * 4);
  float s = v.x + v.y + v.z + v.w;
  float s2 = v.x * v.x + v.y * v.y + v.z * v.z + v.w * v.w;
  for (int m = 1; m < 64; m <<= 1) { s += __shfl_xor(s, m); s2 += __shfl_xor(s2, m); }
  if ((tid & 63) == 0) { ws1[tid >> 6] = s; ws2[tid >> 6] = s2; }
  __syncthreads();
  s = ws1[0] + ws1[1] + ws1[2] + ws1[3];
  s2 = ws2[0] + ws2[1] + ws2[2] + ws2[3];
  float mean = s * (1.f / 1024.f);
  float var = s2 * (1.f / 1024.f) - mean * mean;
  float rstd = rsqrtf(var + 1e-5f);
  float4 gg = *(const float4*)(g + tid * 4);
  float4 bb = *(const float4*)(b + tid * 4);
  float y0 = (v.x - mean) * rstd * gg.x + bb.x;
  float y1 = (v.y - mean) * rstd * gg.y + bb.y;
  float y2 = (v.z - mean) * rstd * gg.z + bb.z;
  float y3 = (v.w - mean) * rstd * gg.w + bb.w;
  if (of) { float4 o = { y0, y1, y2, y3 }; *(float4*)(of + row * 1024 + tid * 4) = o; }
  if (ob) { short4v o = { f2bf(y0), f2bf(y1), f2bf(y2), f2bf(y3) }; *(short4v*)(ob + row * 1024 + tid * 4) = o; }
}

// moe combine + LN2: out = LN(accum + g1*y[pos1] + g2*y[pos2])
__global__ void combine_ln2(const float* __restrict__ accum, const float* __restrict__ y,
                            const int* __restrict__ pos1, const int* __restrict__ pos2,
                            const float* __restrict__ g1a, const float* __restrict__ g2a,
                            const float* __restrict__ gn, const float* __restrict__ bn,
                            float* __restrict__ out) {
  __shared__ float ws1[4], ws2[4];
  int t = blockIdx.x;
  int tid = threadIdx.x;
  const float* a = accum + (long)t * 1024;
  const float* y1 = y + (long)pos1[t] * 1024;
  const float* y2 = y + (long)pos2[t] * 1024;
  float G1 = g1a[t], G2 = g2a[t];
  float4 va = *(const float4*)(a + tid * 4);
  float4 v1 = *(const float4*)(y1 + tid * 4);
  float4 v2 = *(const float4*)(y2 + tid * 4);
  float x0 = va.x + G1 * v1.x + G2 * v2.x;
  float x1 = va.y + G1 * v1.y + G2 * v2.y;
  float x2 = va.z + G1 * v1.z + G2 * v2.z;
  float x3 = va.w + G1 * v1.w + G2 * v2.w;
  float s = x0 + x1 + x2 + x3;
  float s2 = x0 * x0 + x1 * x1 + x2 * x2 + x3 * x3;
  for (int m = 1; m < 64; m <<= 1) { s += __shfl_xor(s, m); s2 += __shfl_xor(s2, m); }
  if ((tid & 63) == 0) { ws1[tid >> 6] = s; ws2[tid >> 6] = s2; }
  __syncthreads();
  s = ws1[0] + ws1[1] + ws1[2] + ws1[3];
  s2 = ws2[0] + ws2[1] + ws2[2] + ws2[3];
  float mean = s * (1.f / 1024.f);
  float var = s2 * (1.f / 1024.f) - mean * mean;
  float rstd = rsqrtf(var + 1e-5f);
  float4 gg = *(const float4*)(gn + tid * 4);
  float4 bb = *(const float4*)(bn + tid * 4);
  float4 o = { (x0 - mean) * rstd * gg.x + bb.x,
               (x1 - mean) * rstd * gg.y + bb.y,
               (x2 - mean) * rstd * gg.z + bb.z,
               (x3 - mean) * rstd * gg.w + bb.w };
  *(float4*)(out + (long)t * 1024 + tid * 4) = o;
}

// router pass 1: one wave per token; NO global atomics.
__global__ void router_compute(const float* __restrict__ x, const float* __restrict__ rw,
                               const float* __restrict__ rb,
                               int* __restrict__ top1, int* __restrict__ top2,
                               float* __restrict__ g1o, float* __restrict__ g2o,
                               float* __restrict__ partialP) {
  __shared__ float pp[4][8];
  int w = threadIdx.x >> 6, lane = threadIdx.x & 63;
  int t = blockIdx.x * 4 + w;
  const float* xp = x + (long)t * 1024;
  float xv[16];
#pragma unroll
  for (int i = 0; i < 16; ++i) xv[i] = xp[lane + i * 64];
  float logit[8];
#pragma unroll
  for (int e = 0; e < 8; ++e) {
    const float* wp = rw + e * 1024;
    double a = 0.0;
#pragma unroll
    for (int i = 0; i < 16; ++i) a += (double)xv[i] * (double)wp[lane + i * 64];
    for (int m = 1; m < 64; m <<= 1) a += __shfl_xor(a, m);
    logit[e] = (float)a + rb[e];
  }
  float mx = logit[0];
#pragma unroll
  for (int e = 1; e < 8; ++e) mx = fmaxf(mx, logit[e]);
  float pe[8], sum = 0.f;
#pragma unroll
  for (int e = 0; e < 8; ++e) { pe[e] = expf(logit[e] - mx); sum += pe[e]; }
  float inv = 1.f / sum;
#pragma unroll
  for (int e = 0; e < 8; ++e) pe[e] *= inv;
  int i1 = 0;
#pragma unroll
  for (int e = 1; e < 8; ++e) if (pe[e] > pe[i1]) i1 = e;
  int i2 = (i1 == 0) ? 1 : 0;
#pragma unroll
  for (int e = 0; e < 8; ++e) if (e != i1 && pe[e] > pe[i2]) i2 = e;
  float denom = pe[i1] + pe[i2];
  if (lane == 0) {
    top1[t] = i1; top2[t] = i2;
    g1o[t] = pe[i1] / denom; g2o[t] = pe[i2] / denom;
#pragma unroll
    for (int e = 0; e < 8; ++e) pp[w][e] = pe[e];
  }
  __syncthreads();
  if (threadIdx.x < 8) {
    partialP[(long)blockIdx.x * 8 + threadIdx.x] =
        pp[0][threadIdx.x] + pp[1][threadIdx.x] + pp[2][threadIdx.x] + pp[3][threadIdx.x];
  }
}

// router pass 2 (ONE block, 1024 threads): probsum reduce, counting-sort
// tokens into packed per-expert lists (contention-free), lb loss.
__global__ void __launch_bounds__(1024) router_finalize(
    const float* __restrict__ partialP,
    const int* __restrict__ top1, const int* __restrict__ top2,
    int* __restrict__ counts, int* __restrict__ eoff_out,
    int* __restrict__ tokList, int* __restrict__ pos1, int* __restrict__ pos2,
    float* __restrict__ lb_out) {
  __shared__ float redP[16][8];
  __shared__ int wtot[16][8];
  __shared__ int tot[8], eoff[8];
  __shared__ float psum[8];
  int tid = threadIdx.x;
  int lane = tid & 63, wv = tid >> 6;

  // probsum reduce: 1024 blocks' partials, one per thread
  float p[8];
#pragma unroll
  for (int e = 0; e < 8; ++e) p[e] = partialP[(long)tid * 8 + e];
  for (int m = 1; m < 64; m <<= 1)
#pragma unroll
    for (int e = 0; e < 8; ++e) p[e] += __shfl_xor(p[e], m);
  if (lane == 0)
#pragma unroll
    for (int e = 0; e < 8; ++e) redP[wv][e] = p[e];

  // per-thread entry counts: entries 8t..8t+7; entry i -> (token i>>1, slot i&1)
  int c[8] = {0, 0, 0, 0, 0, 0, 0, 0};
  int expid[8];
#pragma unroll
  for (int j = 0; j < 8; ++j) {
    int i = tid * 8 + j;
    int t = i >> 1;
    int e = (i & 1) ? top2[t] : top1[t];
    expid[j] = e;
    c[e]++;
  }
  // wave-level inclusive scan per expert
  int inc[8];
#pragma unroll
  for (int e = 0; e < 8; ++e) inc[e] = c[e];
  for (int d = 1; d < 64; d <<= 1) {
#pragma unroll
    for (int e = 0; e < 8; ++e) {
      int o = __shfl_up(inc[e], d);
      if (lane >= d) inc[e] += o;
    }
  }
  if (lane == 63)
#pragma unroll
    for (int e = 0; e < 8; ++e) wtot[wv][e] = inc[e];
  __syncthreads();
  // scan over 16 wave totals (8 threads, 16 serial steps each)
  if (tid < 8) {
    int run = 0;
#pragma unroll
    for (int w = 0; w < 16; ++w) { int v = wtot[w][tid]; wtot[w][tid] = run; run += v; }
    tot[tid] = run;
    float s = 0.f;
#pragma unroll
    for (int w = 0; w < 16; ++w) s += redP[w][tid];
    psum[tid] = s;
  }
  __syncthreads();
  if (tid == 0) {
    int off = 0;
#pragma unroll
    for (int e = 0; e < 8; ++e) { eoff[e] = off; off += tot[e]; }
  }
  __syncthreads();
  // scatter
  int base[8], c2[8] = {0, 0, 0, 0, 0, 0, 0, 0};
#pragma unroll
  for (int e = 0; e < 8; ++e) base[e] = eoff[e] + wtot[wv][e] + inc[e] - c[e];
#pragma unroll
  for (int j = 0; j < 8; ++j) {
    int i = tid * 8 + j;
    int t = i >> 1;
    int e = expid[j];
    int dest = base[e] + c2[e]++;
    tokList[dest] = t;
    if (i & 1) pos2[t] = dest; else pos1[t] = dest;
  }
  if (tid < 8) { counts[tid] = tot[tid]; eoff_out[tid] = eoff[tid]; }
  if (tid == 0) {
    float lb = 0.f;
#pragma unroll
    for (int e = 0; e < 8; ++e)
      lb += ((float)tot[e] / 8192.f) * (psum[e] / 4096.f);
    *lb_out = 8.f * lb;
  }
}

__global__ void sentinel_kernel(float* out, int n) {
  if (threadIdx.x == 0) { out[0] = 1e9f; out[n - 1] = 1e9f; }
}

// ---------------------------------------------------------------------------
extern "C" void kernel_launch(void* const* d_in, const int* in_sizes, int n_in,
                              void* d_out, int out_size, void* d_ws, size_t ws_size,
                              hipStream_t stream) {
  const float* src        = (const float*)d_in[0];
  const float* in_proj_w  = (const float*)d_in[1];
  const float* in_proj_b  = (const float*)d_in[2];
  const float* out_proj_w = (const float*)d_in[3];
  const float* out_proj_b = (const float*)d_in[4];
  const float* ln1_g      = (const float*)d_in[5];
  const float* ln1_b      = (const float*)d_in[6];
  const float* router_w   = (const float*)d_in[7];
  const float* router_b   = (const float*)d_in[8];
  const float* w1         = (const float*)d_in[9];
  const float* b1         = (const float*)d_in[10];
  const float* w2         = (const float*)d_in[11];
  const float* b2         = (const float*)d_in[12];
  const float* ln2_g      = (const float*)d_in[13];
  const float* ln2_b      = (const float*)d_in[14];
  float* out = (float*)d_out;

  char* ws = (char*)d_ws;
  size_t off = 0;
  auto alloc = [&](size_t bytes) -> char* {
    char* p = ws + off;
    off += (bytes + 255) & ~(size_t)255;
    return p;
  };
  // big block: Q/K/V hi+lo planes during attention; w1t/w2t after
  char*  blockW = alloc(8ll * (DFF * DMODEL + DMODEL * DFF) * 2);  // 128MB
  short* Qh = (short*)(blockW + 0ll  * 1024 * 1024);
  short* Ql = (short*)(blockW + 8ll  * 1024 * 1024);
  short* Kh = (short*)(blockW + 16ll * 1024 * 1024);
  short* Kl = (short*)(blockW + 24ll * 1024 * 1024);
  short* Vh = (short*)(blockW + 32ll * 1024 * 1024);
  short* Vl = (short*)(blockW + 40ll * 1024 * 1024);
  short* w1t = (short*)blockW;                                      // [E][dff][d]
  short* w2t = (short*)(blockW + 8ll * DFF * DMODEL * 2);           // [E][d][dff]
  short* winh  = (short*)alloc(3072ll * 1024 * 2);
  short* winl  = (short*)alloc(3072ll * 1024 * 2);
  short* wouth = (short*)alloc(1024ll * 1024 * 2);
  short* woutl = (short*)alloc(1024ll * 1024 * 2);
  short* xh    = (short*)alloc((long)TOKENS * DMODEL * 2);
  short* xl    = (short*)alloc((long)TOKENS * DMODEL * 2);
  char*  reg1  = alloc((long)TOKENS * 3072 * 4);     // 48MB: qkv f32 -> O planes/x1 -> y
  float* qkvf  = (float*)reg1;
  float* Of32  = (float*)reg1;
  short* Ohi   = (short*)(reg1 + 16ll * 1024 * 1024);
  short* Olo   = (short*)(reg1 + 24ll * 1024 * 1024);
  float* x1    = (float*)(reg1 + 32ll * 1024 * 1024);
  float* y     = (float*)reg1;                       // packed expert outputs [8192,1024] f32
  char*  reg2  = alloc(16ll * 1024 * 1024 * 4);      // 64MB: scores chunk -> h
  float* scores = (float*)reg2;
  short* h      = (short*)reg2;
  short* x1nbf = (short*)alloc((long)TOKENS * DMODEL * 2);
  float* accum = (float*)alloc((long)TOKENS * DMODEL * 4);
  float* partialP = (float*)alloc(1024 * 8 * 4);
  int*   top1   = (int*)alloc(TOKENS * 4);
  int*   top2   = (int*)alloc(TOKENS * 4);
  float* g1a    = (float*)alloc(TOKENS * 4);
  float* g2a    = (float*)alloc(TOKENS * 4);
  int*   pos1   = (int*)alloc(TOKENS * 4);
  int*   pos2   = (int*)alloc(TOKENS * 4);
  int*   counts = (int*)alloc(32);
  int*   eoff   = (int*)alloc(32);
  int*   tokList = (int*)alloc(2 * TOKENS * 4);
  size_t needed = off;

  if (ws_size < needed) {
    sentinel_kernel<<<1, 64, 0, stream>>>(out, out_size);
    return;
  }

  // splits of f32 inputs
  split_bf16<<<3072 * 1024 / 1024, 256, 0, stream>>>(in_proj_w, winh, winl, 3072 * 1024);
  split_bf16<<<1024 * 1024 / 1024, 256, 0, stream>>>(out_proj_w, wouth, woutl, 1024 * 1024);
  split_bf16<<<TOKENS * DMODEL / 1024, 256, 0, stream>>>(src, xh, xl, TOKENS * DMODEL);

  // QKV projection (split): qkv f32 = x @ win^T + b
  gemm_nt<128, 128, 64, 64, 1, 0, false, true><<<dim3(32, 24, 1), 256, 0, stream>>>(
      xh, xl, 1024, 0, winh, winl, 1024, 0, qkvf, 3072, 0,
      TOKENS, 3072, 1024, 1.f, in_proj_b, 0, nullptr, nullptr, nullptr, nullptr);
  repack_qkv_split<<<(int)((long)TOKENS * 3072 / 256), 256, 0, stream>>>(qkvf, Qh, Ql, Kh, Kl, Vh, Vl);

  // attention, chunked by batch (16 pairs per chunk)
  for (int c = 0; c < 4; ++c) {
    long co = (long)c * 16 * 65536;
    gemm_nt<128, 128, 64, 64, 1, 0, false, true><<<dim3(8, 8, 16), 256, 0, stream>>>(
        Qh + co, Ql + co, 64, 65536, Kh + co, Kl + co, 64, 65536, scores, 1024, 1048576,
        1024, 1024, 64, 0.125f, nullptr, 0, nullptr, nullptr, nullptr, nullptr);
    softmax_rows_split<<<16 * 1024, 256, 0, stream>>>(scores);
    // P(hi/lo in place, pitch 2048 shorts) @ V^T -> O f32
    gemm_nt<128, 64, 64, 32, 1, 0, false, true><<<dim3(8, 1, 16), 256, 0, stream>>>(
        (const short*)scores, (const short*)scores + 1024, 2048, 2097152,
        Vh + co, Vl + co, 1024, 65536,
        Of32 + (long)c * 1048576, 1024, 64,
        1024, 64, 1024, 1.f, nullptr, 0, nullptr, nullptr, nullptr, nullptr);
  }

  // expert weight transposes now (blockW's Q/K/V no longer needed)
  transpose_bf16<<<dim3(DFF / 64, DMODEL / 64, 8), 256, 0, stream>>>(w1, w1t, DMODEL, DFF);
  transpose_bf16<<<dim3(DMODEL / 64, DFF / 64, 8), 256, 0, stream>>>(w2, w2t, DFF, DMODEL);

  // split O, then out-projection (split) + bias + residual(src) -> x1 f32
  split_bf16<<<TOKENS * DMODEL / 1024, 256, 0, stream>>>(Of32, Ohi, Olo, TOKENS * DMODEL);
  gemm_nt<128, 128, 64, 64, 1, 0, false, true><<<dim3(32, 8, 1), 256, 0, stream>>>(
      Ohi, Olo, 1024, 0, wouth, woutl, 1024, 0, x1, 1024, 0,
      TOKENS, 1024, 1024, 1.f, out_proj_b, 0, src, nullptr, nullptr, nullptr);

  // LN1 -> accum (f32 residual base) + x1nbf (bf16 expert input)
  ln_rows<<<TOKENS, 256, 0, stream>>>(x1, ln1_g, ln1_b, accum, x1nbf);

  // router (atomic-free)
  router_compute<<<TOKENS / 4, 256, 0, stream>>>(accum, router_w, router_b,
                                                 top1, top2, g1a, g2a, partialP);
  router_finalize<<<1, 1024, 0, stream>>>(partialP, top1, top2, counts, eoff,
                                          tokList, pos1, pos2, out + (out_size - 1));

  // expert GEMM1: h = relu(gather(x1nbf) @ w1t[e]^T + b1[e]) (packed bf16)
  gemm_nt<128, 128, 64, 64, 0, 1, true, false><<<dim3(32, 32, 8), 256, 0, stream>>>(
      x1nbf, nullptr, 1024, 0, w1t, nullptr, 1024, (long)DFF * DMODEL, h, DFF, 0,
      0, DFF, 1024, 1.f, b1, DFF, nullptr, tokList, counts, eoff);

  // expert GEMM2: y[packed] = h @ w2t[e]^T + b2[e]  (f32 store, no atomics)
  gemm_nt<128, 128, 64, 64, 1, 2, false, false><<<dim3(32, 8, 8), 256, 0, stream>>>(
      h, nullptr, DFF, 0, w2t, nullptr, DFF, (long)DMODEL * DFF, y, 1024, 0,
      0, DMODEL, DFF, 1.f, b2, DMODEL, nullptr, tokList, counts, eoff);

  // combine + LN2 -> final output
  combine_ln2<<<TOKENS, 256, 0, stream>>>(accum, y, pos1, pos2, g1a, g2a,
                                          ln2_g, ln2_b, out);
}

// Round 4
// 1638.734 us; speedup vs baseline: 1.3653x; 1.0359x over previous
//
#include <hip/hip_runtime.h>

// ---------------------------------------------------------------------------
// TransformerEncoderLayerWithMoE on MI355X (gfx950)
// Round 4: async global_load_lds (16B) GEMM staging with XOR-swizzled LDS
// layout (conflict-free frag reads). Router stays atomic-free.
// ---------------------------------------------------------------------------

typedef __attribute__((ext_vector_type(8))) short short8;   // 8 bf16 = 4 VGPRs
typedef __attribute__((ext_vector_type(4))) short short4v;
typedef __attribute__((ext_vector_type(4))) float floatx4;  // MFMA C/D frag

#define TOKENS 4096
#define DMODEL 1024
#define NHEADS 16
#define DHEAD  64
#define DFF    4096
#define NEXP   8
#define SEQ    1024
#define NPAIR  64   // BATCH*NHEADS

// RNE float->bf16 (finite inputs only)
__device__ inline short f2bf(float f) {
  unsigned u = __builtin_bit_cast(unsigned, f);
  unsigned r = (u + 0x7fffu + ((u >> 16) & 1u)) >> 16;
  return (short)r;
}
__device__ inline float bf2f(short h) {
  return __builtin_bit_cast(float, ((unsigned)(unsigned short)h) << 16);
}

// async 16B/lane global->LDS DMA; lds dest = wave-uniform base + lane*16
__device__ inline void gload16(const short* g, short* l) {
  __builtin_amdgcn_global_load_lds(
      (const __attribute__((address_space(1))) unsigned int*)g,
      (__attribute__((address_space(3))) unsigned int*)l, 16, 0, 0);
}

// ---------------------------------------------------------------------------
// NT GEMM: C[m,n] = scale * sum_k A[m,k]*B[n,k] (+bias[n]) (+src)
// SPLIT: A/B given as hi+lo bf16 planes; acc += Ah*Bh + Ah*Bl + Al*Bh
// EPI: 0 = bf16 store, 1 = f32 store (+optional srcadd)
// AMODE: 0 = linear rows, 1 = gathered rows via packed tokList, 2 = offset rows
// LDS layout: unpadded [rows][32] shorts, 16B chunk c of row r stored at
// chunk position c ^ (r&3) ^ ((r>>2)&3)  (bank-conflict-free, DMA-compatible)
// ---------------------------------------------------------------------------
template<int BM, int BN, int WTM, int WTN, int EPI, int AMODE, bool RELU, bool SPLIT>
__global__ void __launch_bounds__((BM / WTM) * (BN / WTN) * 64)
gemm_nt(const short* __restrict__ Ab, const short* __restrict__ Abl, int lda, long sA,
        const short* __restrict__ Bb, const short* __restrict__ Bbl, int ldb, long sB,
        void* __restrict__ Cb, int ldc, long sC,
        int M, int N, int K, float scale,
        const float* __restrict__ bias, int sBias,
        const float* __restrict__ srcadd,
        const int* __restrict__ tokList,
        const int* __restrict__ counts,
        const int* __restrict__ offsets)
{
  constexpr int WROWS = BM / WTM;
  constexpr int WCOLS = BN / WTN;
  constexpr int NW = WROWS * WCOLS;
  constexpr int MT = WTM / 16;
  constexpr int NT = WTN / 16;
  constexpr int ISSA = (BM / 16) / NW;   // 1024B (16 rows) per wave-issue
  constexpr int ISSB = (BN / 16) / NW;

  const int z = blockIdx.z;
  int Mt = M;
  int rowbase = 0;
  const int* tl = nullptr;
  if (AMODE != 0) {
    Mt = counts[z];
    if ((int)blockIdx.x * BM >= Mt) return;
    if (AMODE == 1) tl = tokList + offsets[z];
    else rowbase = offsets[z];
  }

  const short* A = Ab + (long)z * sA;
  const short* Al = SPLIT ? (Abl + (long)z * sA) : nullptr;
  const short* B = Bb + (long)z * sB;
  const short* Bl = SPLIT ? (Bbl + (long)z * sB) : nullptr;
  const int tid = threadIdx.x;
  const int lane = tid & 63;
  const int w = tid >> 6;
  const int wrow = w % WROWS;
  const int wcol = w / WROWS;
  const int m0 = blockIdx.x * BM;
  const int n0 = blockIdx.y * BN;

  __shared__ __align__(16) short As[(SPLIT ? 2 : 1) * BM * 32];
  __shared__ __align__(16) short Bs[(SPLIT ? 2 : 1) * BN * 32];

  // staging descriptors: lane covers row (lane>>2) of its 16-row segment,
  // source chunk swizzled so frag reads are conflict-free
  const int l4 = lane >> 2;                               // row in segment
  const int lc = (lane & 3) ^ (l4 & 3) ^ ((lane >> 4) & 3); // source 16B chunk
  long agp[ISSA]; int albase[ISSA];
#pragma unroll
  for (int r = 0; r < ISSA; ++r) {
    int seg = w * ISSA + r;
    int row = seg * 16 + l4;
    int grow;
    if (AMODE == 0) grow = m0 + row;
    else if (AMODE == 1) grow = tl[min(m0 + row, Mt - 1)];
    else grow = rowbase + min(m0 + row, Mt - 1);
    agp[r] = (long)grow * lda + lc * 8;
    albase[r] = seg * 512;
  }
  long bgp[ISSB]; int blbase[ISSB];
#pragma unroll
  for (int r = 0; r < ISSB; ++r) {
    int seg = w * ISSB + r;
    int row = seg * 16 + l4;
    bgp[r] = (long)(n0 + row) * ldb + lc * 8;
    blbase[r] = seg * 512;
  }

  floatx4 acc[MT][NT];
#pragma unroll
  for (int i = 0; i < MT; ++i)
#pragma unroll
    for (int j = 0; j < NT; ++j) acc[i][j] = floatx4{0.f, 0.f, 0.f, 0.f};

  // fragment read offsets (swizzle constant per thread: rows step by 16)
  const int am = wrow * WTM + (lane & 15);
  const int bn = wcol * WTN + (lane & 15);
  const int ac = lane >> 4;
  const int aro = am * 32 + ((ac ^ (am & 3) ^ ((am >> 2) & 3)) << 3);
  const int bro = bn * 32 + ((ac ^ (bn & 3) ^ ((bn >> 2) & 3)) << 3);

  for (int k0 = 0; k0 < K; k0 += 32) {
    __syncthreads();
#pragma unroll
    for (int r = 0; r < ISSA; ++r) gload16(A + agp[r] + k0, &As[albase[r]]);
#pragma unroll
    for (int r = 0; r < ISSB; ++r) gload16(B + bgp[r] + k0, &Bs[blbase[r]]);
    if (SPLIT) {
#pragma unroll
      for (int r = 0; r < ISSA; ++r) gload16(Al + agp[r] + k0, &As[BM * 32 + albase[r]]);
#pragma unroll
      for (int r = 0; r < ISSB; ++r) gload16(Bl + bgp[r] + k0, &Bs[BN * 32 + blbase[r]]);
    }
    __syncthreads();

    short8 afh[MT], bfh[NT];
#pragma unroll
    for (int i = 0; i < MT; ++i) afh[i] = *(const short8*)&As[aro + i * 512];
#pragma unroll
    for (int j = 0; j < NT; ++j) bfh[j] = *(const short8*)&Bs[bro + j * 512];
    if (SPLIT) {
      short8 afl[MT], bfl[NT];
#pragma unroll
      for (int i = 0; i < MT; ++i) afl[i] = *(const short8*)&As[BM * 32 + aro + i * 512];
#pragma unroll
      for (int j = 0; j < NT; ++j) bfl[j] = *(const short8*)&Bs[BN * 32 + bro + j * 512];
#pragma unroll
      for (int i = 0; i < MT; ++i)
#pragma unroll
        for (int j = 0; j < NT; ++j) {
          acc[i][j] = __builtin_amdgcn_mfma_f32_16x16x32_bf16(afh[i], bfh[j], acc[i][j], 0, 0, 0);
          acc[i][j] = __builtin_amdgcn_mfma_f32_16x16x32_bf16(afh[i], bfl[j], acc[i][j], 0, 0, 0);
          acc[i][j] = __builtin_amdgcn_mfma_f32_16x16x32_bf16(afl[i], bfh[j], acc[i][j], 0, 0, 0);
        }
    } else {
#pragma unroll
      for (int i = 0; i < MT; ++i)
#pragma unroll
        for (int j = 0; j < NT; ++j)
          acc[i][j] = __builtin_amdgcn_mfma_f32_16x16x32_bf16(afh[i], bfh[j], acc[i][j], 0, 0, 0);
    }
  }

  // epilogue: C layout col=lane&15, row=(lane>>4)*4+q
  const float* bz = bias ? (bias + (long)z * sBias) : nullptr;
#pragma unroll
  for (int i = 0; i < MT; ++i) {
    int rt = wrow * WTM + i * 16 + ((lane >> 4) << 2);
#pragma unroll
    for (int j = 0; j < NT; ++j) {
      int col = n0 + wcol * WTN + j * 16 + (lane & 15);
      float badd = bz ? bz[col] : 0.f;
      floatx4 v = acc[i][j];
#pragma unroll
      for (int q = 0; q < 4; ++q) {
        int r = m0 + rt + q;
        if (AMODE != 0 && r >= Mt) break;
        long orow = (AMODE == 1) ? ((long)offsets[z] + r)
                  : (AMODE == 2) ? ((long)rowbase + r) : (long)r;
        float val = v[q] * scale + badd;
        if (RELU) val = fmaxf(val, 0.f);
        if (EPI == 0) {
          ((short*)Cb)[(long)z * sC + orow * ldc + col] = f2bf(val);
        } else {
          float* Cf = (float*)Cb + (long)z * sC;
          if (srcadd) val += srcadd[orow * ldc + col];
          Cf[orow * ldc + col] = val;
        }
      }
    }
  }
}

// f32 -> hi/lo bf16 planes
__global__ void split_bf16(const float* __restrict__ src, short* __restrict__ hi,
                           short* __restrict__ lo, int n) {
  int i = (blockIdx.x * 256 + threadIdx.x) * 4;
  if (i >= n) return;
  float4 v = *(const float4*)(src + i);
  short h0 = f2bf(v.x), h1 = f2bf(v.y), h2 = f2bf(v.z), h3 = f2bf(v.w);
  short4v oh = { h0, h1, h2, h3 };
  short4v ol = { f2bf(v.x - bf2f(h0)), f2bf(v.y - bf2f(h1)),
                 f2bf(v.z - bf2f(h2)), f2bf(v.w - bf2f(h3)) };
  *(short4v*)(hi + i) = oh;
  *(short4v*)(lo + i) = ol;
}

// f32 [R,C] -> bf16 [C,R] per batch z (R,C multiples of 64)
__global__ void transpose_bf16(const float* __restrict__ src, short* __restrict__ dst,
                               int R, int C) {
  __shared__ float t[64][65];
  long zoff = (long)blockIdx.z * R * C;
  const float* s = src + zoff;
  short* d = dst + zoff;
  int r0 = blockIdx.y * 64, c0 = blockIdx.x * 64;
  int tid = threadIdx.x;
#pragma unroll
  for (int i = 0; i < 16; ++i) {
    int flat = i * 256 + tid;
    int r = flat >> 6, c = flat & 63;
    t[r][c] = s[(long)(r0 + r) * C + c0 + c];
  }
  __syncthreads();
#pragma unroll
  for (int i = 0; i < 16; ++i) {
    int flat = i * 256 + tid;
    int c = flat >> 6, r = flat & 63;
    d[(long)(c0 + c) * R + r0 + r] = f2bf(t[r][c]);
  }
}

// qkv f32 [T,3072] -> Q,K hi/lo [pair][S][dh], Vt hi/lo [pair][dh][S]
__global__ void repack_qkv_split(const float* __restrict__ qkv,
                                 short* __restrict__ Qh, short* __restrict__ Ql,
                                 short* __restrict__ Kh, short* __restrict__ Kl,
                                 short* __restrict__ Vh, short* __restrict__ Vl) {
  long idx = (long)blockIdx.x * 256 + threadIdx.x;
  int t = (int)(idx / 3072), c = (int)(idx % 3072);
  int sec = c >> 10, within = c & 1023;
  int h = within >> 6, di = within & 63;
  int b = t >> 10, s = t & 1023;
  int g = b * NHEADS + h;
  float v = qkv[idx];
  short vh = f2bf(v);
  short vl = f2bf(v - bf2f(vh));
  if (sec == 2) {
    long vo = (long)g * 65536 + di * 1024 + s;
    Vh[vo] = vh; Vl[vo] = vl;
  } else {
    long qo = (long)g * 65536 + s * 64 + di;
    if (sec == 0) { Qh[qo] = vh; Ql[qo] = vl; }
    else          { Kh[qo] = vh; Kl[qo] = vl; }
  }
}

// row softmax on f32, write P as hi plane [0,1024) + lo plane [1024,2048) shorts
__global__ void softmax_rows_split(float* __restrict__ scores) {
  __shared__ float wred[4], wsum[4];
  long row = blockIdx.x;
  float* p = scores + row * 1024;
  int tid = threadIdx.x;
  float4 v = *(const float4*)(p + tid * 4);
  float mx = fmaxf(fmaxf(v.x, v.y), fmaxf(v.z, v.w));
  for (int m = 1; m < 64; m <<= 1) mx = fmaxf(mx, __shfl_xor(mx, m));
  if ((tid & 63) == 0) wred[tid >> 6] = mx;
  __syncthreads();
  mx = fmaxf(fmaxf(wred[0], wred[1]), fmaxf(wred[2], wred[3]));
  float e0 = expf(v.x - mx), e1 = expf(v.y - mx), e2 = expf(v.z - mx), e3 = expf(v.w - mx);
  float sm = e0 + e1 + e2 + e3;
  for (int m = 1; m < 64; m <<= 1) sm += __shfl_xor(sm, m);
  if ((tid & 63) == 0) wsum[tid >> 6] = sm;
  __syncthreads();
  float inv = 1.f / (wsum[0] + wsum[1] + wsum[2] + wsum[3]);
  float y0 = e0 * inv, y1 = e1 * inv, y2 = e2 * inv, y3 = e3 * inv;
  short h0 = f2bf(y0), h1 = f2bf(y1), h2 = f2bf(y2), h3 = f2bf(y3);
  short4v oh = { h0, h1, h2, h3 };
  short4v ol = { f2bf(y0 - bf2f(h0)), f2bf(y1 - bf2f(h1)),
                 f2bf(y2 - bf2f(h2)), f2bf(y3 - bf2f(h3)) };
  short* ps = (short*)p;
  *(short4v*)(ps + tid * 4) = oh;
  *(short4v*)(ps + 1024 + tid * 4) = ol;
}

// layer norm over rows of 1024; optional f32 and bf16 outputs
__global__ void ln_rows(const float* __restrict__ x, const float* __restrict__ g,
                        const float* __restrict__ b, float* __restrict__ of,
                        short* __restrict__ ob) {
  __shared__ float ws1[4], ws2[4];
  long row = blockIdx.x;
  const float* p = x + row * 1024;
  int tid = threadIdx.x;
  float4 v = *(const float4*)(p + tid * 4);
  float s = v.x + v.y + v.z + v.w;
  float s2 = v.x * v.x + v.y * v.y + v.z * v.z + v.w * v.w;
  for (int m = 1; m < 64; m <<= 1) { s += __shfl_xor(s, m); s2 += __shfl_xor(s2, m); }
  if ((tid & 63) == 0) { ws1[tid >> 6] = s; ws2[tid >> 6] = s2; }
  __syncthreads();
  s = ws1[0] + ws1[1] + ws1[2] + ws1[3];
  s2 = ws2[0] + ws2[1] + ws2[2] + ws2[3];
  float mean = s * (1.f / 1024.f);
  float var = s2 * (1.f / 1024.f) - mean * mean;
  float rstd = rsqrtf(var + 1e-5f);
  float4 gg = *(const float4*)(g + tid * 4);
  float4 bb = *(const float4*)(b + tid * 4);
  float y0 = (v.x - mean) * rstd * gg.x + bb.x;
  float y1 = (v.y - mean) * rstd * gg.y + bb.y;
  float y2 = (v.z - mean) * rstd * gg.z + bb.z;
  float y3 = (v.w - mean) * rstd * gg.w + bb.w;
  if (of) { float4 o = { y0, y1, y2, y3 }; *(float4*)(of + row * 1024 + tid * 4) = o; }
  if (ob) { short4v o = { f2bf(y0), f2bf(y1), f2bf(y2), f2bf(y3) }; *(short4v*)(ob + row * 1024 + tid * 4) = o; }
}

// moe combine + LN2: out = LN(accum + g1*y[pos1] + g2*y[pos2])
__global__ void combine_ln2(const float* __restrict__ accum, const float* __restrict__ y,
                            const int* __restrict__ pos1, const int* __restrict__ pos2,
                            const float* __restrict__ g1a, const float* __restrict__ g2a,
                            const float* __restrict__ gn, const float* __restrict__ bn,
                            float* __restrict__ out) {
  __shared__ float ws1[4], ws2[4];
  int t = blockIdx.x;
  int tid = threadIdx.x;
  const float* a = accum + (long)t * 1024;
  const float* y1 = y + (long)pos1[t] * 1024;
  const float* y2 = y + (long)pos2[t] * 1024;
  float G1 = g1a[t], G2 = g2a[t];
  float4 va = *(const float4*)(a + tid * 4);
  float4 v1 = *(const float4*)(y1 + tid * 4);
  float4 v2 = *(const float4*)(y2 + tid * 4);
  float x0 = va.x + G1 * v1.x + G2 * v2.x;
  float x1 = va.y + G1 * v1.y + G2 * v2.y;
  float x2 = va.z + G1 * v1.z + G2 * v2.z;
  float x3 = va.w + G1 * v1.w + G2 * v2.w;
  float s = x0 + x1 + x2 + x3;
  float s2 = x0 * x0 + x1 * x1 + x2 * x2 + x3 * x3;
  for (int m = 1; m < 64; m <<= 1) { s += __shfl_xor(s, m); s2 += __shfl_xor(s2, m); }
  if ((tid & 63) == 0) { ws1[tid >> 6] = s; ws2[tid >> 6] = s2; }
  __syncthreads();
  s = ws1[0] + ws1[1] + ws1[2] + ws1[3];
  s2 = ws2[0] + ws2[1] + ws2[2] + ws2[3];
  float mean = s * (1.f / 1024.f);
  float var = s2 * (1.f / 1024.f) - mean * mean;
  float rstd = rsqrtf(var + 1e-5f);
  float4 gg = *(const float4*)(gn + tid * 4);
  float4 bb = *(const float4*)(bn + tid * 4);
  float4 o = { (x0 - mean) * rstd * gg.x + bb.x,
               (x1 - mean) * rstd * gg.y + bb.y,
               (x2 - mean) * rstd * gg.z + bb.z,
               (x3 - mean) * rstd * gg.w + bb.w };
  *(float4*)(out + (long)t * 1024 + tid * 4) = o;
}

// router pass 1: one wave per token; NO global atomics.
__global__ void router_compute(const float* __restrict__ x, const float* __restrict__ rw,
                               const float* __restrict__ rb,
                               int* __restrict__ top1, int* __restrict__ top2,
                               float* __restrict__ g1o, float* __restrict__ g2o,
                               float* __restrict__ partialP) {
  __shared__ float pp[4][8];
  int w = threadIdx.x >> 6, lane = threadIdx.x & 63;
  int t = blockIdx.x * 4 + w;
  const float* xp = x + (long)t * 1024;
  float xv[16];
#pragma unroll
  for (int i = 0; i < 16; ++i) xv[i] = xp[lane + i * 64];
  float logit[8];
#pragma unroll
  for (int e = 0; e < 8; ++e) {
    const float* wp = rw + e * 1024;
    double a = 0.0;
#pragma unroll
    for (int i = 0; i < 16; ++i) a += (double)xv[i] * (double)wp[lane + i * 64];
    for (int m = 1; m < 64; m <<= 1) a += __shfl_xor(a, m);
    logit[e] = (float)a + rb[e];
  }
  float mx = logit[0];
#pragma unroll
  for (int e = 1; e < 8; ++e) mx = fmaxf(mx, logit[e]);
  float pe[8], sum = 0.f;
#pragma unroll
  for (int e = 0; e < 8; ++e) { pe[e] = expf(logit[e] - mx); sum += pe[e]; }
  float inv = 1.f / sum;
#pragma unroll
  for (int e = 0; e < 8; ++e) pe[e] *= inv;
  int i1 = 0;
#pragma unroll
  for (int e = 1; e < 8; ++e) if (pe[e] > pe[i1]) i1 = e;
  int i2 = (i1 == 0) ? 1 : 0;
#pragma unroll
  for (int e = 0; e < 8; ++e) if (e != i1 && pe[e] > pe[i2]) i2 = e;
  float denom = pe[i1] + pe[i2];
  if (lane == 0) {
    top1[t] = i1; top2[t] = i2;
    g1o[t] = pe[i1] / denom; g2o[t] = pe[i2] / denom;
#pragma unroll
    for (int e = 0; e < 8; ++e) pp[w][e] = pe[e];
  }
  __syncthreads();
  if (threadIdx.x < 8) {
    partialP[(long)blockIdx.x * 8 + threadIdx.x] =
        pp[0][threadIdx.x] + pp[1][threadIdx.x] + pp[2][threadIdx.x] + pp[3][threadIdx.x];
  }
}

// router pass 2 (ONE block, 1024 threads): probsum reduce, counting-sort
// tokens into packed per-expert lists (contention-free), lb loss.
__global__ void __launch_bounds__(1024) router_finalize(
    const float* __restrict__ partialP,
    const int* __restrict__ top1, const int* __restrict__ top2,
    int* __restrict__ counts, int* __restrict__ eoff_out,
    int* __restrict__ tokList, int* __restrict__ pos1, int* __restrict__ pos2,
    float* __restrict__ lb_out) {
  __shared__ float redP[16][8];
  __shared__ int wtot[16][8];
  __shared__ int tot[8], eoff[8];
  __shared__ float psum[8];
  int tid = threadIdx.x;
  int lane = tid & 63, wv = tid >> 6;

  float p[8];
#pragma unroll
  for (int e = 0; e < 8; ++e) p[e] = partialP[(long)tid * 8 + e];
  for (int m = 1; m < 64; m <<= 1)
#pragma unroll
    for (int e = 0; e < 8; ++e) p[e] += __shfl_xor(p[e], m);
  if (lane == 0)
#pragma unroll
    for (int e = 0; e < 8; ++e) redP[wv][e] = p[e];

  int c[8] = {0, 0, 0, 0, 0, 0, 0, 0};
  int expid[8];
#pragma unroll
  for (int j = 0; j < 8; ++j) {
    int i = tid * 8 + j;
    int t = i >> 1;
    int e = (i & 1) ? top2[t] : top1[t];
    expid[j] = e;
    c[e]++;
  }
  int inc[8];
#pragma unroll
  for (int e = 0; e < 8; ++e) inc[e] = c[e];
  for (int d = 1; d < 64; d <<= 1) {
#pragma unroll
    for (int e = 0; e < 8; ++e) {
      int o = __shfl_up(inc[e], d);
      if (lane >= d) inc[e] += o;
    }
  }
  if (lane == 63)
#pragma unroll
    for (int e = 0; e < 8; ++e) wtot[wv][e] = inc[e];
  __syncthreads();
  if (tid < 8) {
    int run = 0;
#pragma unroll
    for (int w = 0; w < 16; ++w) { int v = wtot[w][tid]; wtot[w][tid] = run; run += v; }
    tot[tid] = run;
    float s = 0.f;
#pragma unroll
    for (int w = 0; w < 16; ++w) s += redP[w][tid];
    psum[tid] = s;
  }
  __syncthreads();
  if (tid == 0) {
    int off = 0;
#pragma unroll
    for (int e = 0; e < 8; ++e) { eoff[e] = off; off += tot[e]; }
  }
  __syncthreads();
  int base[8], c2[8] = {0, 0, 0, 0, 0, 0, 0, 0};
#pragma unroll
  for (int e = 0; e < 8; ++e) base[e] = eoff[e] + wtot[wv][e] + inc[e] - c[e];
#pragma unroll
  for (int j = 0; j < 8; ++j) {
    int i = tid * 8 + j;
    int t = i >> 1;
    int e = expid[j];
    int dest = base[e] + c2[e]++;
    tokList[dest] = t;
    if (i & 1) pos2[t] = dest; else pos1[t] = dest;
  }
  if (tid < 8) { counts[tid] = tot[tid]; eoff_out[tid] = eoff[tid]; }
  if (tid == 0) {
    float lb = 0.f;
#pragma unroll
    for (int e = 0; e < 8; ++e)
      lb += ((float)tot[e] / 8192.f) * (psum[e] / 4096.f);
    *lb_out = 8.f * lb;
  }
}

__global__ void sentinel_kernel(float* out, int n) {
  if (threadIdx.x == 0) { out[0] = 1e9f; out[n - 1] = 1e9f; }
}

// ---------------------------------------------------------------------------
extern "C" void kernel_launch(void* const* d_in, const int* in_sizes, int n_in,
                              void* d_out, int out_size, void* d_ws, size_t ws_size,
                              hipStream_t stream) {
  const float* src        = (const float*)d_in[0];
  const float* in_proj_w  = (const float*)d_in[1];
  const float* in_proj_b  = (const float*)d_in[2];
  const float* out_proj_w = (const float*)d_in[3];
  const float* out_proj_b = (const float*)d_in[4];
  const float* ln1_g      = (const float*)d_in[5];
  const float* ln1_b      = (const float*)d_in[6];
  const float* router_w   = (const float*)d_in[7];
  const float* router_b   = (const float*)d_in[8];
  const float* w1         = (const float*)d_in[9];
  const float* b1         = (const float*)d_in[10];
  const float* w2         = (const float*)d_in[11];
  const float* b2         = (const float*)d_in[12];
  const float* ln2_g      = (const float*)d_in[13];
  const float* ln2_b      = (const float*)d_in[14];
  float* out = (float*)d_out;

  char* ws = (char*)d_ws;
  size_t off = 0;
  auto alloc = [&](size_t bytes) -> char* {
    char* p = ws + off;
    off += (bytes + 255) & ~(size_t)255;
    return p;
  };
  // big block: Q/K/V hi+lo planes during attention; w1t/w2t after
  char*  blockW = alloc(8ll * (DFF * DMODEL + DMODEL * DFF) * 2);  // 128MB
  short* Qh = (short*)(blockW + 0ll  * 1024 * 1024);
  short* Ql = (short*)(blockW + 8ll  * 1024 * 1024);
  short* Kh = (short*)(blockW + 16ll * 1024 * 1024);
  short* Kl = (short*)(blockW + 24ll * 1024 * 1024);
  short* Vh = (short*)(blockW + 32ll * 1024 * 1024);
  short* Vl = (short*)(blockW + 40ll * 1024 * 1024);
  short* w1t = (short*)blockW;                                      // [E][dff][d]
  short* w2t = (short*)(blockW + 8ll * DFF * DMODEL * 2);           // [E][d][dff]
  short* winh  = (short*)alloc(3072ll * 1024 * 2);
  short* winl  = (short*)alloc(3072ll * 1024 * 2);
  short* wouth = (short*)alloc(1024ll * 1024 * 2);
  short* woutl = (short*)alloc(1024ll * 1024 * 2);
  short* xh    = (short*)alloc((long)TOKENS * DMODEL * 2);
  short* xl    = (short*)alloc((long)TOKENS * DMODEL * 2);
  char*  reg1  = alloc((long)TOKENS * 3072 * 4);     // 48MB: qkv f32 -> O planes/x1 -> y
  float* qkvf  = (float*)reg1;
  float* Of32  = (float*)reg1;
  short* Ohi   = (short*)(reg1 + 16ll * 1024 * 1024);
  short* Olo   = (short*)(reg1 + 24ll * 1024 * 1024);
  float* x1    = (float*)(reg1 + 32ll * 1024 * 1024);
  float* y     = (float*)reg1;                       // packed expert outputs [8192,1024] f32
  char*  reg2  = alloc(16ll * 1024 * 1024 * 4);      // 64MB: scores chunk -> h
  float* scores = (float*)reg2;
  short* h      = (short*)reg2;
  short* x1nbf = (short*)alloc((long)TOKENS * DMODEL * 2);
  float* accum = (float*)alloc((long)TOKENS * DMODEL * 4);
  float* partialP = (float*)alloc(1024 * 8 * 4);
  int*   top1   = (int*)alloc(TOKENS * 4);
  int*   top2   = (int*)alloc(TOKENS * 4);
  float* g1a    = (float*)alloc(TOKENS * 4);
  float* g2a    = (float*)alloc(TOKENS * 4);
  int*   pos1   = (int*)alloc(TOKENS * 4);
  int*   pos2   = (int*)alloc(TOKENS * 4);
  int*   counts = (int*)alloc(32);
  int*   eoff   = (int*)alloc(32);
  int*   tokList = (int*)alloc(2 * TOKENS * 4);
  size_t needed = off;

  if (ws_size < needed) {
    sentinel_kernel<<<1, 64, 0, stream>>>(out, out_size);
    return;
  }

  // splits of f32 inputs
  split_bf16<<<3072 * 1024 / 1024, 256, 0, stream>>>(in_proj_w, winh, winl, 3072 * 1024);
  split_bf16<<<1024 * 1024 / 1024, 256, 0, stream>>>(out_proj_w, wouth, woutl, 1024 * 1024);
  split_bf16<<<TOKENS * DMODEL / 1024, 256, 0, stream>>>(src, xh, xl, TOKENS * DMODEL);

  // QKV projection (split): qkv f32 = x @ win^T + b
  gemm_nt<128, 128, 64, 64, 1, 0, false, true><<<dim3(32, 24, 1), 256, 0, stream>>>(
      xh, xl, 1024, 0, winh, winl, 1024, 0, qkvf, 3072, 0,
      TOKENS, 3072, 1024, 1.f, in_proj_b, 0, nullptr, nullptr, nullptr, nullptr);
  repack_qkv_split<<<(int)((long)TOKENS * 3072 / 256), 256, 0, stream>>>(qkvf, Qh, Ql, Kh, Kl, Vh, Vl);

  // attention, chunked by batch (16 pairs per chunk)
  for (int c = 0; c < 4; ++c) {
    long co = (long)c * 16 * 65536;
    gemm_nt<128, 128, 64, 64, 1, 0, false, true><<<dim3(8, 8, 16), 256, 0, stream>>>(
        Qh + co, Ql + co, 64, 65536, Kh + co, Kl + co, 64, 65536, scores, 1024, 1048576,
        1024, 1024, 64, 0.125f, nullptr, 0, nullptr, nullptr, nullptr, nullptr);
    softmax_rows_split<<<16 * 1024, 256, 0, stream>>>(scores);
    // P(hi/lo in place, pitch 2048 shorts) @ V^T -> O f32
    gemm_nt<128, 64, 64, 32, 1, 0, false, true><<<dim3(8, 1, 16), 256, 0, stream>>>(
        (const short*)scores, (const short*)scores + 1024, 2048, 2097152,
        Vh + co, Vl + co, 1024, 65536,
        Of32 + (long)c * 1048576, 1024, 64,
        1024, 64, 1024, 1.f, nullptr, 0, nullptr, nullptr, nullptr, nullptr);
  }

  // expert weight transposes now (blockW's Q/K/V no longer needed)
  transpose_bf16<<<dim3(DFF / 64, DMODEL / 64, 8), 256, 0, stream>>>(w1, w1t, DMODEL, DFF);
  transpose_bf16<<<dim3(DMODEL / 64, DFF / 64, 8), 256, 0, stream>>>(w2, w2t, DFF, DMODEL);

  // split O, then out-projection (split) + bias + residual(src) -> x1 f32
  split_bf16<<<TOKENS * DMODEL / 1024, 256, 0, stream>>>(Of32, Ohi, Olo, TOKENS * DMODEL);
  gemm_nt<128, 128, 64, 64, 1, 0, false, true><<<dim3(32, 8, 1), 256, 0, stream>>>(
      Ohi, Olo, 1024, 0, wouth, woutl, 1024, 0, x1, 1024, 0,
      TOKENS, 1024, 1024, 1.f, out_proj_b, 0, src, nullptr, nullptr, nullptr);

  // LN1 -> accum (f32 residual base) + x1nbf (bf16 expert input)
  ln_rows<<<TOKENS, 256, 0, stream>>>(x1, ln1_g, ln1_b, accum, x1nbf);

  // router (atomic-free)
  router_compute<<<TOKENS / 4, 256, 0, stream>>>(accum, router_w, router_b,
                                                 top1, top2, g1a, g2a, partialP);
  router_finalize<<<1, 1024, 0, stream>>>(partialP, top1, top2, counts, eoff,
                                          tokList, pos1, pos2, out + (out_size - 1));

  // expert GEMM1: h = relu(gather(x1nbf) @ w1t[e]^T + b1[e]) (packed bf16)
  gemm_nt<128, 128, 64, 64, 0, 1, true, false><<<dim3(32, 32, 8), 256, 0, stream>>>(
      x1nbf, nullptr, 1024, 0, w1t, nullptr, 1024, (long)DFF * DMODEL, h, DFF, 0,
      0, DFF, 1024, 1.f, b1, DFF, nullptr, tokList, counts, eoff);

  // expert GEMM2: y[packed] = h @ w2t[e]^T + b2[e]  (f32 store, no atomics)
  gemm_nt<128, 128, 64, 64, 1, 2, false, false><<<dim3(32, 8, 8), 256, 0, stream>>>(
      h, nullptr, DFF, 0, w2t, nullptr, DFF, (long)DMODEL * DFF, y, 1024, 0,
      0, DMODEL, DFF, 1.f, b2, DMODEL, nullptr, tokList, counts, eoff);

  // combine + LN2 -> final output
  combine_ln2<<<TOKENS, 256, 0, stream>>>(accum, y, pos1, pos2, g1a, g2a,
                                          ln2_g, ln2_b, out);
}